// Round 3
// baseline (109.709 us; speedup 1.0000x reference)
//
#include <hip/hip_runtime.h>
#include <hip/hip_bf16.h>
#include <math.h>

#define N 4096
#define NGRP 16   // level-1 reduction groups

__inline__ __device__ float waveReduceSum(float v) {
    #pragma unroll
    for (int o = 32; o > 0; o >>= 1) v += __shfl_down(v, o);
    return v;
}

// Combined: blocks [0, nWh) compute wh partials over CHUNK-row chunks;
// blocks [nWh, nWh+4096) compute wx[j] = relu(dot(x, w_in[j,:])).
template<int CHUNK>
__global__ __launch_bounds__(256) void k_combo1(const float* __restrict__ x,
                                                const float* __restrict__ w_in,
                                                const float* __restrict__ hid,
                                                const float* __restrict__ w,
                                                const float* __restrict__ alpha,
                                                const float* __restrict__ hebb,
                                                float* __restrict__ part,
                                                float* __restrict__ wx_out,
                                                int nWh) {
    if ((int)blockIdx.x < nWh) {
        int bid = blockIdx.x;
        int xt  = bid & 3;                 // 4 column tiles of 1024
        int cy  = bid >> 2;                // chunk index
        int j0  = xt * 1024 + threadIdx.x * 4;
        int i0  = cy * CHUNK;
        float hv[CHUNK];
        #pragma unroll
        for (int r = 0; r < CHUNK; ++r) hv[r] = hid[i0 + r];
        float4 acc = make_float4(0.f, 0.f, 0.f, 0.f);
        #pragma unroll
        for (int r = 0; r < CHUNK; ++r) {
            size_t off = (size_t)(i0 + r) * N + j0;
            float4 wv = *reinterpret_cast<const float4*>(w + off);
            float4 av = *reinterpret_cast<const float4*>(alpha + off);
            float4 bv = *reinterpret_cast<const float4*>(hebb + off);
            acc.x = fmaf(hv[r], fmaf(av.x, bv.x, wv.x), acc.x);
            acc.y = fmaf(hv[r], fmaf(av.y, bv.y, wv.y), acc.y);
            acc.z = fmaf(hv[r], fmaf(av.z, bv.z, wv.z), acc.z);
            acc.w = fmaf(hv[r], fmaf(av.w, bv.w, wv.w), acc.w);
        }
        *reinterpret_cast<float4*>(part + (size_t)cy * N + j0) = acc;
    } else {
        int j = blockIdx.x - nWh;
        const float4* row = reinterpret_cast<const float4*>(w_in + (size_t)j * N);
        const float4* xv  = reinterpret_cast<const float4*>(x);
        float sum = 0.f;
        #pragma unroll
        for (int k = threadIdx.x; k < N / 4; k += 256) {
            float4 a = row[k], c = xv[k];
            sum += a.x * c.x + a.y * c.y + a.z * c.z + a.w * c.w;
        }
        sum = waveReduceSum(sum);
        __shared__ float wsum[4];
        int wid = threadIdx.x >> 6, lane = threadIdx.x & 63;
        if (lane == 0) wsum[wid] = sum;
        __syncthreads();
        if (threadIdx.x == 0)
            wx_out[j] = fmaxf(wsum[0] + wsum[1] + wsum[2] + wsum[3], 0.f);
    }
}

// eta partials, same pattern, single matrix
template<int CHUNK>
__global__ __launch_bounds__(256) void k_eta_part(const float* __restrict__ wh,
                                                  const float* __restrict__ pe,
                                                  float* __restrict__ part) {
    int bid = blockIdx.x;
    int xt  = bid & 3;
    int cy  = bid >> 2;
    int j0  = xt * 1024 + threadIdx.x * 4;
    int i0  = cy * CHUNK;
    float hv[CHUNK];
    #pragma unroll
    for (int r = 0; r < CHUNK; ++r) hv[r] = wh[i0 + r];
    float4 acc = make_float4(0.f, 0.f, 0.f, 0.f);
    #pragma unroll
    for (int r = 0; r < CHUNK; ++r) {
        size_t off = (size_t)(i0 + r) * N + j0;
        float4 pv = *reinterpret_cast<const float4*>(pe + off);
        acc.x = fmaf(hv[r], pv.x, acc.x);
        acc.y = fmaf(hv[r], pv.y, acc.y);
        acc.z = fmaf(hv[r], pv.z, acc.z);
        acc.w = fmaf(hv[r], pv.w, acc.w);
    }
    *reinterpret_cast<float4*>(part + (size_t)cy * N + j0) = acc;
}

// level-1 reduction: part2[g*N + j] = sum_{c in group g} part[c*N + j]
__global__ __launch_bounds__(256) void k_red(const float* __restrict__ part,
                                             float* __restrict__ part2,
                                             int cpg) {
    int g  = blockIdx.y;
    int j0 = (blockIdx.x * 256 + threadIdx.x) * 4;
    const float4* p4 = reinterpret_cast<const float4*>(part);
    float4 s = make_float4(0.f, 0.f, 0.f, 0.f);
    #pragma unroll 8
    for (int c = 0; c < cpg; ++c) {
        float4 v = p4[((size_t)(g * cpg + c) * N + j0) >> 2];
        s.x += v.x; s.y += v.y; s.z += v.z; s.w += v.w;
    }
    *reinterpret_cast<float4*>(part2 + (size_t)g * N + j0) = s;
}

// finalize wh from part2 (+b), s = wx + wh, LayerNorm, relu -> wy; also writes wh
__global__ __launch_bounds__(1024) void k_ln(const float* __restrict__ part2,
                                             const float* __restrict__ b,
                                             const float* __restrict__ wx,
                                             const float* __restrict__ gamma,
                                             const float* __restrict__ beta,
                                             float* __restrict__ wh_out,
                                             float* __restrict__ wy_out) {
    __shared__ float red[16];
    __shared__ float bc[2];
    int tid = threadIdx.x;
    int wid = tid >> 6, lane = tid & 63;
    float sv[4];
    float lsum = 0.f;
    #pragma unroll
    for (int q = 0; q < 4; ++q) {
        int j = q * 1024 + tid;
        float acc = b[j];
        #pragma unroll
        for (int g = 0; g < NGRP; ++g) acc += part2[(size_t)g * N + j];
        wh_out[j] = acc;
        float s = acc + wx[j];
        sv[q] = s;
        lsum += s;
    }
    float wv = waveReduceSum(lsum);
    if (lane == 0) red[wid] = wv;
    __syncthreads();
    if (tid < 64) {
        float t = (tid < 16) ? red[tid] : 0.f;
        t = waveReduceSum(t);
        if (tid == 0) bc[0] = t * (1.f / N);
    }
    __syncthreads();
    float mean = bc[0];
    __syncthreads();
    float lsq = 0.f;
    #pragma unroll
    for (int q = 0; q < 4; ++q) { float d = sv[q] - mean; lsq += d * d; }
    wv = waveReduceSum(lsq);
    if (lane == 0) red[wid] = wv;
    __syncthreads();
    if (tid < 64) {
        float t = (tid < 16) ? red[tid] : 0.f;
        t = waveReduceSum(t);
        if (tid == 0) bc[1] = t * (1.f / N);
    }
    __syncthreads();
    float rstd = rsqrtf(bc[1] + 1e-5f);
    #pragma unroll
    for (int q = 0; q < 4; ++q) {
        int j = q * 1024 + tid;
        float ln = fmaf(gamma[j] * (sv[q] - mean), rstd, beta[j]);
        wy_out[j] = fmaxf(ln, 0.f);
    }
}

// eta[j] = sigmoid(pb[j] + sum_g part2[g*N + j])
__global__ __launch_bounds__(256) void k_eta_fin(const float* __restrict__ part2,
                                                 const float* __restrict__ pb,
                                                 float* __restrict__ eta) {
    int j0 = (blockIdx.x * 256 + threadIdx.x) * 4;
    float4 s = *reinterpret_cast<const float4*>(pb + j0);
    #pragma unroll
    for (int g = 0; g < NGRP; ++g) {
        float4 v = *reinterpret_cast<const float4*>(part2 + (size_t)g * N + j0);
        s.x += v.x; s.y += v.y; s.z += v.z; s.w += v.w;
    }
    float4 r;
    r.x = 1.f / (1.f + expf(-s.x));
    r.y = 1.f / (1.f + expf(-s.y));
    r.z = 1.f / (1.f + expf(-s.z));
    r.w = 1.f / (1.f + expf(-s.w));
    *reinterpret_cast<float4*>(eta + j0) = r;
}

// hebb_new[i,j] = (1-lamda)*hebb[i,j] + eta[i]*hid[i]*wh[j]; one block per row
__global__ __launch_bounds__(256) void k_hebb(const float* __restrict__ hebb,
                                              const float* __restrict__ eta,
                                              const float* __restrict__ hid,
                                              const float* __restrict__ wh,
                                              const float* __restrict__ lamda,
                                              float* __restrict__ out) {
    int i  = blockIdx.x;
    float decay = 1.f - lamda[0];
    float coef  = eta[i] * hid[i];
    size_t base = (size_t)i * N;
    int j0 = threadIdx.x * 16;
    #pragma unroll
    for (int q = 0; q < 4; ++q) {
        int j = j0 + q * 4;
        float4 h  = *reinterpret_cast<const float4*>(hebb + base + j);
        float4 w4 = *reinterpret_cast<const float4*>(wh + j);
        float4 r;
        r.x = fmaf(decay, h.x, coef * w4.x);
        r.y = fmaf(decay, h.y, coef * w4.y);
        r.z = fmaf(decay, h.z, coef * w4.z);
        r.w = fmaf(decay, h.w, coef * w4.w);
        *reinterpret_cast<float4*>(out + base + j) = r;
    }
}

extern "C" void kernel_launch(void* const* d_in, const int* in_sizes, int n_in,
                              void* d_out, int out_size, void* d_ws, size_t ws_size,
                              hipStream_t stream) {
    const float* x         = (const float*)d_in[0];
    const float* hid       = (const float*)d_in[1];
    const float* hebb      = (const float*)d_in[2];
    const float* w_in      = (const float*)d_in[3];
    const float* w         = (const float*)d_in[4];
    const float* alpha     = (const float*)d_in[5];
    const float* b         = (const float*)d_in[6];
    const float* lamda     = (const float*)d_in[7];
    const float* pred_eta  = (const float*)d_in[8];
    const float* pred_eta_b= (const float*)d_in[9];
    const float* ln_gamma  = (const float*)d_in[10];
    const float* ln_beta   = (const float*)d_in[11];

    float* wy       = (float*)d_out;
    float* hebb_out = (float*)d_out + N;

    // pick CHUNK by available workspace
    const size_t needF8 = ((size_t)(N / 8) * N) + (size_t)NGRP * N + 3 * N;
    bool big = (ws_size / 4) >= needF8;

    float* ws = (float*)d_ws;
    int nchunk = big ? (N / 8) : (N / 32);
    float* part  = ws;
    float* part2 = ws + (size_t)nchunk * N;
    float* wx    = part2 + (size_t)NGRP * N;
    float* wh    = wx + N;
    float* eta   = wh + N;
    int cpg = nchunk / NGRP;

    if (big) {
        int nWh = 4 * (N / 8);   // 2048
        k_combo1<8><<<nWh + N, 256, 0, stream>>>(x, w_in, hid, w, alpha, hebb, part, wx, nWh);
        k_red    <<<dim3(4, NGRP), 256, 0, stream>>>(part, part2, cpg);
        k_ln     <<<1, 1024, 0, stream>>>(part2, b, wx, ln_gamma, ln_beta, wh, wy);
        k_eta_part<8><<<nWh, 256, 0, stream>>>(wh, pred_eta, part);
        k_red    <<<dim3(4, NGRP), 256, 0, stream>>>(part, part2, cpg);
        k_eta_fin<<<4, 256, 0, stream>>>(part2, pred_eta_b, eta);
    } else {
        int nWh = 4 * (N / 32);  // 512
        k_combo1<32><<<nWh + N, 256, 0, stream>>>(x, w_in, hid, w, alpha, hebb, part, wx, nWh);
        k_red    <<<dim3(4, NGRP), 256, 0, stream>>>(part, part2, cpg);
        k_ln     <<<1, 1024, 0, stream>>>(part2, b, wx, ln_gamma, ln_beta, wh, wy);
        k_eta_part<32><<<nWh, 256, 0, stream>>>(wh, pred_eta, part);
        k_red    <<<dim3(4, NGRP), 256, 0, stream>>>(part, part2, cpg);
        k_eta_fin<<<4, 256, 0, stream>>>(part2, pred_eta_b, eta);
    }
    k_hebb<<<N, 256, 0, stream>>>(hebb, eta, hid, wh, lamda, hebb_out);
}